// Round 1
// baseline (3711.963 us; speedup 1.0000x reference)
//
#include <hip/hip_runtime.h>
#include <hip/hip_bf16.h>
#include <cstddef>

// ---------------------------------------------------------------------------
// Generic tiled SGEMM: C[M,Nout] = act(A[M,K] @ W[K,Nout] + bias)
// BM=BN=64, BK=16, 256 threads, 4x4 micro-tile per thread.
// LDS kk-major so fragment reads are contiguous (ds_read_b128-able).
// ---------------------------------------------------------------------------
template <bool RELU, bool BIAS>
__global__ __launch_bounds__(256) void dense_kernel(
    const float* __restrict__ A, const float* __restrict__ W,
    const float* __restrict__ bias, float* __restrict__ C,
    int M, int K, int Nout)
{
    __shared__ float As[16][68];   // [kk][row], pad 68 -> 16B-aligned rows, low conflict
    __shared__ float Ws[16][68];   // [kk][col]

    const int tid = threadIdx.x;
    const int tx  = tid & 15;      // output col group (4 cols)
    const int ty  = tid >> 4;      // output row group (4 rows)
    const int bm  = blockIdx.x * 64;
    const int bn  = blockIdx.y * 64;

    const int arow = tid >> 2;           // 0..63  (tile row for A load)
    const int acol = (tid & 3) * 4;      // 0..12  (k offset for A load)
    const int wrow = tid >> 4;           // 0..15  (k for W load)
    const int wcol = (tid & 15) * 4;     // 0..60  (col for W load)

    float acc[4][4] = {};

    for (int k0 = 0; k0 < K; k0 += 16) {
        // ---- global loads (guarded) ----
        float4 av = {0.f, 0.f, 0.f, 0.f};
        {
            int gr = bm + arow;
            if (gr < M) av = *(const float4*)(A + (size_t)gr * K + (k0 + acol));
        }
        float4 wv = {0.f, 0.f, 0.f, 0.f};
        {
            int gc = bn + wcol;
            // Nout is a multiple of 4 for every call site (256,128,40) -> all-or-nothing
            if (gc + 3 < Nout) wv = *(const float4*)(W + (size_t)(k0 + wrow) * Nout + gc);
        }
        __syncthreads();   // previous iteration's LDS reads done before overwrite
        As[acol + 0][arow] = av.x;
        As[acol + 1][arow] = av.y;
        As[acol + 2][arow] = av.z;
        As[acol + 3][arow] = av.w;
        Ws[wrow][wcol + 0] = wv.x;
        Ws[wrow][wcol + 1] = wv.y;
        Ws[wrow][wcol + 2] = wv.z;
        Ws[wrow][wcol + 3] = wv.w;
        __syncthreads();

        #pragma unroll
        for (int kk = 0; kk < 16; ++kk) {
            const float a0 = As[kk][ty * 4 + 0];
            const float a1 = As[kk][ty * 4 + 1];
            const float a2 = As[kk][ty * 4 + 2];
            const float a3 = As[kk][ty * 4 + 3];
            const float b0 = Ws[kk][tx * 4 + 0];
            const float b1 = Ws[kk][tx * 4 + 1];
            const float b2 = Ws[kk][tx * 4 + 2];
            const float b3 = Ws[kk][tx * 4 + 3];
            acc[0][0] += a0 * b0; acc[0][1] += a0 * b1; acc[0][2] += a0 * b2; acc[0][3] += a0 * b3;
            acc[1][0] += a1 * b0; acc[1][1] += a1 * b1; acc[1][2] += a1 * b2; acc[1][3] += a1 * b3;
            acc[2][0] += a2 * b0; acc[2][1] += a2 * b1; acc[2][2] += a2 * b2; acc[2][3] += a2 * b3;
            acc[3][0] += a3 * b0; acc[3][1] += a3 * b1; acc[3][2] += a3 * b2; acc[3][3] += a3 * b3;
        }
    }

    // ---- epilogue ----
    float bv[4] = {0.f, 0.f, 0.f, 0.f};
    if (BIAS) {
        #pragma unroll
        for (int j = 0; j < 4; ++j) {
            int gc = bn + tx * 4 + j;
            if (gc < Nout) bv[j] = bias[gc];
        }
    }
    const int gc0 = bn + tx * 4;
    #pragma unroll
    for (int i = 0; i < 4; ++i) {
        int gr = bm + ty * 4 + i;
        if (gr >= M) continue;
        float v0 = acc[i][0] + bv[0];
        float v1 = acc[i][1] + bv[1];
        float v2 = acc[i][2] + bv[2];
        float v3 = acc[i][3] + bv[3];
        if (RELU) {
            v0 = fmaxf(v0, 0.f); v1 = fmaxf(v1, 0.f);
            v2 = fmaxf(v2, 0.f); v3 = fmaxf(v3, 0.f);
        }
        if (gc0 + 3 < Nout) {
            float4 o = {v0, v1, v2, v3};
            *(float4*)(C + (size_t)gr * Nout + gc0) = o;
        } else {
            if (gc0 + 0 < Nout) C[(size_t)gr * Nout + gc0 + 0] = v0;
            if (gc0 + 1 < Nout) C[(size_t)gr * Nout + gc0 + 1] = v1;
            if (gc0 + 2 < Nout) C[(size_t)gr * Nout + gc0 + 2] = v2;
            if (gc0 + 3 < Nout) C[(size_t)gr * Nout + gc0 + 3] = v3;
        }
    }
}

// ---------------------------------------------------------------------------
// agg[dst[e]] += hw[src[e]]   (32 threads per edge, float4 each, f32 atomics)
// ---------------------------------------------------------------------------
__global__ __launch_bounds__(256) void scatter_add_kernel(
    const float* __restrict__ hw, const int* __restrict__ src,
    const int* __restrict__ dst, float* __restrict__ agg, int E)
{
    long long idx = (long long)blockIdx.x * 256 + threadIdx.x;
    int e = (int)(idx >> 5);
    if (e >= E) return;
    int lane = (int)(idx & 31);
    int s = src[e];
    int d = dst[e];
    float4 v = *(const float4*)(hw + (size_t)s * 128 + lane * 4);
    float* o = agg + (size_t)d * 128 + lane * 4;
    atomicAdd(o + 0, v.x);
    atomicAdd(o + 1, v.y);
    atomicAdd(o + 2, v.z);
    atomicAdd(o + 3, v.w);
}

// ---------------------------------------------------------------------------
// h = relu(agg + bias[col]),  row width 128 floats = 32 float4
// ---------------------------------------------------------------------------
__global__ __launch_bounds__(256) void relu_bias_kernel(
    const float* __restrict__ agg, const float* __restrict__ b,
    float* __restrict__ h, int total4)
{
    int i = blockIdx.x * 256 + threadIdx.x;
    if (i >= total4) return;
    float4 v  = ((const float4*)agg)[i];
    float4 bb = ((const float4*)b)[i & 31];
    v.x = fmaxf(v.x + bb.x, 0.f);
    v.y = fmaxf(v.y + bb.y, 0.f);
    v.z = fmaxf(v.z + bb.z, 0.f);
    v.w = fmaxf(v.w + bb.w, 0.f);
    ((float4*)h)[i] = v;
}

// ---------------------------------------------------------------------------
// out = log_softmax(logits) over 40 cols, one wave (64 lanes) per row
// ---------------------------------------------------------------------------
__global__ __launch_bounds__(256) void log_softmax_kernel(
    const float* __restrict__ logits, float* __restrict__ out, int M)
{
    int w    = (int)(((long long)blockIdx.x * 256 + threadIdx.x) >> 6);
    int lane = threadIdx.x & 63;
    if (w >= M) return;
    float v = -3.402823466e38f;
    if (lane < 40) v = logits[(size_t)w * 40 + lane];
    float m = v;
    #pragma unroll
    for (int off = 32; off > 0; off >>= 1) m = fmaxf(m, __shfl_xor(m, off, 64));
    float e = (lane < 40) ? expf(v - m) : 0.f;
    float s = e;
    #pragma unroll
    for (int off = 32; off > 0; off >>= 1) s += __shfl_xor(s, off, 64);
    float ls = logf(s);
    if (lane < 40) out[(size_t)w * 40 + lane] = v - m - ls;
}

// ---------------------------------------------------------------------------
extern "C" void kernel_launch(void* const* d_in, const int* in_sizes, int n_in,
                              void* d_out, int out_size, void* d_ws, size_t ws_size,
                              hipStream_t stream)
{
    const float* x      = (const float*)d_in[0];
    const int*   edge   = (const int*)d_in[1];
    const float* enc_w1 = (const float*)d_in[2];
    const float* enc_b1 = (const float*)d_in[3];
    const float* enc_w2 = (const float*)d_in[4];
    const float* enc_b2 = (const float*)d_in[5];
    const float* gcn_w  = (const float*)d_in[6];
    const float* gcn_b  = (const float*)d_in[7];
    const float* dec_w1 = (const float*)d_in[8];
    const float* dec_b1 = (const float*)d_in[9];
    const float* dec_w2 = (const float*)d_in[10];
    const float* dec_b2 = (const float*)d_in[11];

    const int F_IN = 128, H_ENC = 256, D = 128, N_CLS = 40, R = 3;
    const int N = in_sizes[0] / F_IN;   // 100000
    const int E = in_sizes[1] / 2;      // 600000

    const int* src = edge;
    const int* dst = edge + E;

    // workspace layout (floats):
    //   wsA : N*256   (enc hidden; later: [hw | agg] ping-pong halves)
    //   wsB : N*128   (h)
    float* wsA = (float*)d_ws;
    float* wsB = wsA + (size_t)N * H_ENC;
    float* hw  = wsA;                       // N*128
    float* agg = wsA + (size_t)N * D;       // N*128 (also reused for logits)
    float* out = (float*)d_out;

    dim3 blk(256);
    const int gmx = (N + 63) / 64;

    // encoder: h1 = relu(x@W1+b1) [N,256]; h = h1@W2+b2 [N,128]
    dense_kernel<true, true><<<dim3(gmx, (H_ENC + 63) / 64), blk, 0, stream>>>(
        x, enc_w1, enc_b1, wsA, N, F_IN, H_ENC);
    dense_kernel<false, true><<<dim3(gmx, (D + 63) / 64), blk, 0, stream>>>(
        wsA, enc_w2, enc_b2, wsB, N, H_ENC, D);

    // 3-hop GCN
    const int sblocks = (int)(((long long)E * 32 + 255) / 256);
    const int rb      = (N * D / 4 + 255) / 256;
    for (int r = 0; r < R; ++r) {
        dense_kernel<false, false><<<dim3(gmx, (D + 63) / 64), blk, 0, stream>>>(
            wsB, gcn_w + (size_t)r * D * D, nullptr, hw, N, D, D);
        hipMemsetAsync(agg, 0, (size_t)N * D * sizeof(float), stream);
        scatter_add_kernel<<<sblocks, blk, 0, stream>>>(hw, src, dst, agg, E);
        relu_bias_kernel<<<rb, blk, 0, stream>>>(agg, gcn_b + (size_t)r * D, wsB, N * D / 4);
    }

    // decoder: h2 = relu(h@W1+b1); logits = h2@W2+b2; out = log_softmax(logits)
    dense_kernel<true, true><<<dim3(gmx, (D + 63) / 64), blk, 0, stream>>>(
        wsB, dec_w1, dec_b1, wsA, N, D, D);
    dense_kernel<false, true><<<dim3(gmx, 1), blk, 0, stream>>>(
        wsA, dec_w2, dec_b2, agg /*logits*/, N, D, N_CLS);

    const int smb = (N + 3) / 4;   // 4 waves/block, 1 row/wave
    log_softmax_kernel<<<smb, blk, 0, stream>>>(agg, out, N);
}

// Round 4
// 891.938 us; speedup vs baseline: 4.1617x; 4.1617x over previous
//
#include <hip/hip_runtime.h>
#include <hip/hip_bf16.h>
#include <cstddef>

// ---------------------------------------------------------------------------
// Generic tiled SGEMM: C[M,Nout] = act(A[M,K] @ W[K,Nout] + bias)
// BM=BN=64, BK=16, 256 threads, 4x4 micro-tile per thread.
// ---------------------------------------------------------------------------
template <bool RELU, bool BIAS>
__global__ __launch_bounds__(256) void dense_kernel(
    const float* __restrict__ A, const float* __restrict__ W,
    const float* __restrict__ bias, float* __restrict__ C,
    int M, int K, int Nout)
{
    __shared__ float As[16][68];
    __shared__ float Ws[16][68];

    const int tid = threadIdx.x;
    const int tx  = tid & 15;
    const int ty  = tid >> 4;
    const int bm  = blockIdx.x * 64;
    const int bn  = blockIdx.y * 64;

    const int arow = tid >> 2;
    const int acol = (tid & 3) * 4;
    const int wrow = tid >> 4;
    const int wcol = (tid & 15) * 4;

    float acc[4][4] = {};

    for (int k0 = 0; k0 < K; k0 += 16) {
        float4 av = {0.f, 0.f, 0.f, 0.f};
        {
            int gr = bm + arow;
            if (gr < M) av = *(const float4*)(A + (size_t)gr * K + (k0 + acol));
        }
        float4 wv = {0.f, 0.f, 0.f, 0.f};
        {
            int gc = bn + wcol;
            if (gc + 3 < Nout) wv = *(const float4*)(W + (size_t)(k0 + wrow) * Nout + gc);
        }
        __syncthreads();
        As[acol + 0][arow] = av.x;
        As[acol + 1][arow] = av.y;
        As[acol + 2][arow] = av.z;
        As[acol + 3][arow] = av.w;
        Ws[wrow][wcol + 0] = wv.x;
        Ws[wrow][wcol + 1] = wv.y;
        Ws[wrow][wcol + 2] = wv.z;
        Ws[wrow][wcol + 3] = wv.w;
        __syncthreads();

        #pragma unroll
        for (int kk = 0; kk < 16; ++kk) {
            const float a0 = As[kk][ty * 4 + 0];
            const float a1 = As[kk][ty * 4 + 1];
            const float a2 = As[kk][ty * 4 + 2];
            const float a3 = As[kk][ty * 4 + 3];
            const float b0 = Ws[kk][tx * 4 + 0];
            const float b1 = Ws[kk][tx * 4 + 1];
            const float b2 = Ws[kk][tx * 4 + 2];
            const float b3 = Ws[kk][tx * 4 + 3];
            acc[0][0] += a0 * b0; acc[0][1] += a0 * b1; acc[0][2] += a0 * b2; acc[0][3] += a0 * b3;
            acc[1][0] += a1 * b0; acc[1][1] += a1 * b1; acc[1][2] += a1 * b2; acc[1][3] += a1 * b3;
            acc[2][0] += a2 * b0; acc[2][1] += a2 * b1; acc[2][2] += a2 * b2; acc[2][3] += a2 * b3;
            acc[3][0] += a3 * b0; acc[3][1] += a3 * b1; acc[3][2] += a3 * b2; acc[3][3] += a3 * b3;
        }
    }

    float bv[4] = {0.f, 0.f, 0.f, 0.f};
    if (BIAS) {
        #pragma unroll
        for (int j = 0; j < 4; ++j) {
            int gc = bn + tx * 4 + j;
            if (gc < Nout) bv[j] = bias[gc];
        }
    }
    const int gc0 = bn + tx * 4;
    #pragma unroll
    for (int i = 0; i < 4; ++i) {
        int gr = bm + ty * 4 + i;
        if (gr >= M) continue;
        float v0 = acc[i][0] + bv[0];
        float v1 = acc[i][1] + bv[1];
        float v2 = acc[i][2] + bv[2];
        float v3 = acc[i][3] + bv[3];
        if (RELU) {
            v0 = fmaxf(v0, 0.f); v1 = fmaxf(v1, 0.f);
            v2 = fmaxf(v2, 0.f); v3 = fmaxf(v3, 0.f);
        }
        if (gc0 + 3 < Nout) {
            float4 o = {v0, v1, v2, v3};
            *(float4*)(C + (size_t)gr * Nout + gc0) = o;
        } else {
            if (gc0 + 0 < Nout) C[(size_t)gr * Nout + gc0 + 0] = v0;
            if (gc0 + 1 < Nout) C[(size_t)gr * Nout + gc0 + 1] = v1;
            if (gc0 + 2 < Nout) C[(size_t)gr * Nout + gc0 + 2] = v2;
            if (gc0 + 3 < Nout) C[(size_t)gr * Nout + gc0 + 3] = v3;
        }
    }
}

// ---------------------------------------------------------------------------
// CSR build: histogram -> exclusive scan -> fill
// ---------------------------------------------------------------------------
__global__ __launch_bounds__(256) void degree_kernel(
    const int* __restrict__ dst, int* __restrict__ cnt, int E)
{
    int e = blockIdx.x * 256 + threadIdx.x;
    if (e < E) atomicAdd(&cnt[dst[e]], 1);
}

// per-block exclusive scan of cnt -> rs, block sums -> partials
__global__ __launch_bounds__(256) void scan_block_kernel(
    const int* __restrict__ cnt, int* __restrict__ rs,
    int* __restrict__ partials, int N)
{
    __shared__ int sm[256];
    int i = blockIdx.x * 256 + threadIdx.x;
    int v = (i < N) ? cnt[i] : 0;
    sm[threadIdx.x] = v;
    __syncthreads();
    #pragma unroll
    for (int off = 1; off < 256; off <<= 1) {
        int t = (threadIdx.x >= off) ? sm[threadIdx.x - off] : 0;
        __syncthreads();
        sm[threadIdx.x] += t;
        __syncthreads();
    }
    if (i < N) rs[i] = sm[threadIdx.x] - v;   // exclusive within block
    if (threadIdx.x == 255) partials[blockIdx.x] = sm[255];
}

// single-block scan of partials (nblk <= 512), in-place to exclusive
__global__ __launch_bounds__(512) void scan_partials_kernel(
    int* __restrict__ partials, int nblk)
{
    __shared__ int sm[512];
    int v = (threadIdx.x < nblk) ? partials[threadIdx.x] : 0;
    sm[threadIdx.x] = v;
    __syncthreads();
    #pragma unroll
    for (int off = 1; off < 512; off <<= 1) {
        int t = (threadIdx.x >= off) ? sm[threadIdx.x - off] : 0;
        __syncthreads();
        sm[threadIdx.x] += t;
        __syncthreads();
    }
    if (threadIdx.x < nblk) partials[threadIdx.x] = sm[threadIdx.x] - v;
}

__global__ __launch_bounds__(256) void add_offsets_kernel(
    int* __restrict__ rs, const int* __restrict__ partials, int N, int E)
{
    int i = blockIdx.x * 256 + threadIdx.x;
    if (i < N) rs[i] += partials[blockIdx.x];
    if (i == N) rs[N] = E;   // total
}

__global__ __launch_bounds__(256) void fill_kernel(
    const int* __restrict__ src, const int* __restrict__ dst,
    const int* __restrict__ rs, int* __restrict__ cursor,
    int* __restrict__ csr_src, int E)
{
    int e = blockIdx.x * 256 + threadIdx.x;
    if (e >= E) return;
    int d = dst[e];
    int pos = rs[d] + atomicAdd(&cursor[d], 1);
    csr_src[pos] = src[e];
}

// ---------------------------------------------------------------------------
// Gather-based aggregation, fused bias+relu:
//   hout[n] = relu( sum_{e in in(n)} hw[csr_src[e]] + bias )
// One wave (64 lanes) per node, float2 per lane (128 cols).
// ---------------------------------------------------------------------------
__global__ __launch_bounds__(256) void gather_agg_kernel(
    const float* __restrict__ hw, const int* __restrict__ csr_src,
    const int* __restrict__ rs, const float* __restrict__ bias,
    float* __restrict__ hout, int N)
{
    int node = (blockIdx.x * 256 + threadIdx.x) >> 6;   // uniform per wave
    if (node >= N) return;
    int lane = threadIdx.x & 63;
    int beg = rs[node];
    int end = rs[node + 1];
    float2 acc = {0.f, 0.f};
    for (int i = beg; i < end; ++i) {
        int s = csr_src[i];
        float2 v = *(const float2*)(hw + (size_t)s * 128 + lane * 2);
        acc.x += v.x;
        acc.y += v.y;
    }
    float2 b = *(const float2*)(bias + lane * 2);
    acc.x = fmaxf(acc.x + b.x, 0.f);
    acc.y = fmaxf(acc.y + b.y, 0.f);
    *(float2*)(hout + (size_t)node * 128 + lane * 2) = acc;
}

// ---------------------------------------------------------------------------
// out = log_softmax(logits) over 40 cols, one wave per row
// ---------------------------------------------------------------------------
__global__ __launch_bounds__(256) void log_softmax_kernel(
    const float* __restrict__ logits, float* __restrict__ out, int M)
{
    int w    = (int)(((long long)blockIdx.x * 256 + threadIdx.x) >> 6);
    int lane = threadIdx.x & 63;
    if (w >= M) return;
    float v = -3.402823466e38f;
    if (lane < 40) v = logits[(size_t)w * 40 + lane];
    float m = v;
    #pragma unroll
    for (int off = 32; off > 0; off >>= 1) m = fmaxf(m, __shfl_xor(m, off, 64));
    float e = (lane < 40) ? expf(v - m) : 0.f;
    float s = e;
    #pragma unroll
    for (int off = 32; off > 0; off >>= 1) s += __shfl_xor(s, off, 64);
    float ls = logf(s);
    if (lane < 40) out[(size_t)w * 40 + lane] = v - m - ls;
}

// ---------------------------------------------------------------------------
extern "C" void kernel_launch(void* const* d_in, const int* in_sizes, int n_in,
                              void* d_out, int out_size, void* d_ws, size_t ws_size,
                              hipStream_t stream)
{
    const float* x      = (const float*)d_in[0];
    const int*   edge   = (const int*)d_in[1];
    const float* enc_w1 = (const float*)d_in[2];
    const float* enc_b1 = (const float*)d_in[3];
    const float* enc_w2 = (const float*)d_in[4];
    const float* enc_b2 = (const float*)d_in[5];
    const float* gcn_w  = (const float*)d_in[6];
    const float* gcn_b  = (const float*)d_in[7];
    const float* dec_w1 = (const float*)d_in[8];
    const float* dec_b1 = (const float*)d_in[9];
    const float* dec_w2 = (const float*)d_in[10];
    const float* dec_b2 = (const float*)d_in[11];

    const int F_IN = 128, H_ENC = 256, D = 128, N_CLS = 40, R = 3;
    const int N = in_sizes[0] / F_IN;   // 100000
    const int E = in_sizes[1] / 2;      // 600000

    const int* src = edge;
    const int* dst = edge + E;

    // ---- workspace layout ----
    // A  : N*256 floats  (enc hidden; then A1 = hw / h2, A2 = CSR ints / logits)
    // B  : N*128 floats  (h)
    float* A  = (float*)d_ws;
    float* B  = A + (size_t)N * H_ENC;
    float* A1 = A;                         // N*128 floats: hw, later h2
    float* A2 = A + (size_t)N * D;         // N*128 floats: CSR ints, later logits

    int* csr_src = (int*)A2;               // E ints
    int* rs      = csr_src + E;            // N+1 ints
    int* cnt     = rs + (N + 1);           // N ints (histogram, then cursor)
    int* partials = cnt + N;               // <=512 ints

    float* logits = A2;                    // N*40 floats (after CSR is dead)
    float* out    = (float*)d_out;

    dim3 blk(256);
    const int gmx    = (N + 63) / 64;
    const int nblkN  = (N + 255) / 256;        // 391
    const int nblkE  = (E + 255) / 256;

    // encoder
    dense_kernel<true, true><<<dim3(gmx, (H_ENC + 63) / 64), blk, 0, stream>>>(
        x, enc_w1, enc_b1, A, N, F_IN, H_ENC);
    dense_kernel<false, true><<<dim3(gmx, (D + 63) / 64), blk, 0, stream>>>(
        A, enc_w2, enc_b2, B, N, H_ENC, D);

    // ---- CSR build (once per launch; A region free after enc2) ----
    hipMemsetAsync(cnt, 0, (size_t)N * sizeof(int), stream);
    degree_kernel<<<nblkE, blk, 0, stream>>>(dst, cnt, E);
    scan_block_kernel<<<nblkN, blk, 0, stream>>>(cnt, rs, partials, N);
    scan_partials_kernel<<<1, 512, 0, stream>>>(partials, nblkN);
    add_offsets_kernel<<<nblkN + 1, blk, 0, stream>>>(rs, partials, N, E);
    hipMemsetAsync(cnt, 0, (size_t)N * sizeof(int), stream);   // reuse as cursor
    fill_kernel<<<nblkE, blk, 0, stream>>>(src, dst, rs, cnt, csr_src, E);

    // ---- 3-hop GCN: transform -> gather-aggregate(+bias+relu) ----
    const int aggb = (N * 64 + 255) / 256;   // one wave per node
    for (int r = 0; r < R; ++r) {
        dense_kernel<false, false><<<dim3(gmx, (D + 63) / 64), blk, 0, stream>>>(
            B, gcn_w + (size_t)r * D * D, nullptr, A1, N, D, D);
        gather_agg_kernel<<<aggb, blk, 0, stream>>>(
            A1, csr_src, rs, gcn_b + (size_t)r * D, B, N);
    }

    // ---- decoder ----
    dense_kernel<true, true><<<dim3(gmx, (D + 63) / 64), blk, 0, stream>>>(
        B, dec_w1, dec_b1, A1, N, D, D);
    dense_kernel<false, true><<<dim3(gmx, 1), blk, 0, stream>>>(
        A1, dec_w2, dec_b2, logits, N, D, N_CLS);

    const int smb = (N + 3) / 4;
    log_softmax_kernel<<<smb, blk, 0, stream>>>(logits, out, N);
}

// Round 5
// 734.242 us; speedup vs baseline: 5.0555x; 1.2148x over previous
//
#include <hip/hip_runtime.h>
#include <hip/hip_bf16.h>
#include <cstddef>

typedef __attribute__((ext_vector_type(8))) short short8v;   // 8 x bf16 = 4 VGPR
typedef __attribute__((ext_vector_type(4))) float f32x4;     // MFMA accumulator

__device__ inline ushort f2bf(float f) {                     // f32 -> bf16 RNE
    uint u = __float_as_uint(f);
    uint r = (u + 0x7fffu + ((u >> 16) & 1u)) >> 16;
    return (ushort)r;
}
__device__ inline float bflo(uint v) { return __uint_as_float(v << 16); }
__device__ inline float bfhi(uint v) { return __uint_as_float(v & 0xffff0000u); }

// ---------------------------------------------------------------------------
// cast f32 -> bf16, 4 elements/thread
// ---------------------------------------------------------------------------
__global__ __launch_bounds__(256) void cast_bf16_kernel(
    const float* __restrict__ in, ushort* __restrict__ out, int n4)
{
    int i = blockIdx.x * 256 + threadIdx.x;
    if (i >= n4) return;
    float4 v = ((const float4*)in)[i];
    ushort4 o = { f2bf(v.x), f2bf(v.y), f2bf(v.z), f2bf(v.w) };
    ((ushort4*)out)[i] = o;
}

// ---------------------------------------------------------------------------
// W[K][Nout] f32  ->  Wt[rows][K] bf16  (rows >= Nout, zero-padded)
// ---------------------------------------------------------------------------
__global__ __launch_bounds__(256) void wtrans_kernel(
    const float* __restrict__ W, ushort* __restrict__ Wt,
    int K, int Nout, int rows)
{
    int idx = blockIdx.x * 256 + threadIdx.x;
    if (idx >= rows * K) return;
    int r = idx / K;
    int c = idx - r * K;
    float v = (r < Nout) ? W[(size_t)c * Nout + r] : 0.f;
    Wt[idx] = f2bf(v);
}

// ---------------------------------------------------------------------------
// bf16 MFMA dense: C[M,Ncols] = act(A[M,K] @ Wt^T + bias)
//   A  : bf16 [M][K] row-major
//   Wt : bf16 [NT*16][K] row-major (pre-transposed weight, zero-padded cols)
// 4 waves/block, 16 rows/wave, NT 16-col tiles/wave, LDS-free.
// Fragment map (m201-verified): a: row=base+fr, k=k0+fq*8; b: col=n*16+fr,
// same k; D: row=base+fq*4+j, col=n*16+fr.
// ---------------------------------------------------------------------------
template <bool RELU, int NT, bool OUTF32, bool BIAS>
__global__ __launch_bounds__(256) void dense_mfma_kernel(
    const ushort* __restrict__ A, const ushort* __restrict__ Wt,
    const float* __restrict__ bias, void* __restrict__ Cout,
    int M, int K, int Ncols)
{
    const int tid  = threadIdx.x;
    const int wave = tid >> 6;
    const int lane = tid & 63;
    const int fr   = lane & 15;
    const int fq   = lane >> 4;

    const int rowA = blockIdx.x * 64 + wave * 16 + fr;       // A row this lane feeds
    const int rA   = (rowA < M) ? rowA : (M - 1);            // clamp OOB loads

    f32x4 acc[NT];
    #pragma unroll
    for (int n = 0; n < NT; ++n) acc[n] = (f32x4){0.f, 0.f, 0.f, 0.f};

    const int ksteps = K >> 5;
    for (int ks = 0; ks < ksteps; ++ks) {
        const int k0 = ks * 32 + fq * 8;
        short8v a = *(const short8v*)(A + (size_t)rA * K + k0);
        #pragma unroll
        for (int n = 0; n < NT; ++n) {
            short8v b = *(const short8v*)(Wt + (size_t)(n * 16 + fr) * K + k0);
            acc[n] = __builtin_amdgcn_mfma_f32_16x16x32_bf16(a, b, acc[n], 0, 0, 0);
        }
    }

    const int rbase = blockIdx.x * 64 + wave * 16 + fq * 4;
    #pragma unroll
    for (int n = 0; n < NT; ++n) {
        int col = n * 16 + fr;
        if (col >= Ncols) continue;                          // dec2 (40 of 48)
        float bv = 0.f;
        if (BIAS) bv = bias[col];
        #pragma unroll
        for (int j = 0; j < 4; ++j) {
            int r = rbase + j;
            if (r >= M) continue;
            float v = acc[n][j] + bv;
            if (RELU) v = fmaxf(v, 0.f);
            if (OUTF32) ((float*)Cout)[(size_t)r * Ncols + col] = v;
            else        ((ushort*)Cout)[(size_t)r * Ncols + col] = f2bf(v);
        }
    }
}

// ---------------------------------------------------------------------------
// CSR build: histogram -> exclusive scan -> fill   (unchanged, R4-verified)
// ---------------------------------------------------------------------------
__global__ __launch_bounds__(256) void degree_kernel(
    const int* __restrict__ dst, int* __restrict__ cnt, int E)
{
    int e = blockIdx.x * 256 + threadIdx.x;
    if (e < E) atomicAdd(&cnt[dst[e]], 1);
}

__global__ __launch_bounds__(256) void scan_block_kernel(
    const int* __restrict__ cnt, int* __restrict__ rs,
    int* __restrict__ partials, int N)
{
    __shared__ int sm[256];
    int i = blockIdx.x * 256 + threadIdx.x;
    int v = (i < N) ? cnt[i] : 0;
    sm[threadIdx.x] = v;
    __syncthreads();
    #pragma unroll
    for (int off = 1; off < 256; off <<= 1) {
        int t = (threadIdx.x >= off) ? sm[threadIdx.x - off] : 0;
        __syncthreads();
        sm[threadIdx.x] += t;
        __syncthreads();
    }
    if (i < N) rs[i] = sm[threadIdx.x] - v;
    if (threadIdx.x == 255) partials[blockIdx.x] = sm[255];
}

__global__ __launch_bounds__(512) void scan_partials_kernel(
    int* __restrict__ partials, int nblk)
{
    __shared__ int sm[512];
    int v = (threadIdx.x < nblk) ? partials[threadIdx.x] : 0;
    sm[threadIdx.x] = v;
    __syncthreads();
    #pragma unroll
    for (int off = 1; off < 512; off <<= 1) {
        int t = (threadIdx.x >= off) ? sm[threadIdx.x - off] : 0;
        __syncthreads();
        sm[threadIdx.x] += t;
        __syncthreads();
    }
    if (threadIdx.x < nblk) partials[threadIdx.x] = sm[threadIdx.x] - v;
}

__global__ __launch_bounds__(256) void add_offsets_kernel(
    int* __restrict__ rs, const int* __restrict__ partials, int N, int E)
{
    int i = blockIdx.x * 256 + threadIdx.x;
    if (i < N) rs[i] += partials[blockIdx.x];
    if (i == N) rs[N] = E;
}

__global__ __launch_bounds__(256) void fill_kernel(
    const int* __restrict__ src, const int* __restrict__ dst,
    const int* __restrict__ rs, int* __restrict__ cursor,
    int* __restrict__ csr_src, int E)
{
    int e = blockIdx.x * 256 + threadIdx.x;
    if (e >= E) return;
    int d = dst[e];
    int pos = rs[d] + atomicAdd(&cursor[d], 1);
    csr_src[pos] = src[e];
}

// ---------------------------------------------------------------------------
// hout[n] = relu( sum_{e in in(n)} hw[csr_src[e]] + bias )   all bf16 I/O,
// f32 accumulate. One wave/node, 2 cols/lane (uint = 2 bf16).
// ---------------------------------------------------------------------------
__global__ __launch_bounds__(256) void gather_agg_kernel(
    const ushort* __restrict__ hw, const int* __restrict__ csr_src,
    const int* __restrict__ rs, const float* __restrict__ bias,
    ushort* __restrict__ hout, int N)
{
    int node = (blockIdx.x * 256 + threadIdx.x) >> 6;
    if (node >= N) return;
    int lane = threadIdx.x & 63;
    int beg = rs[node];
    int end = rs[node + 1];
    float ax = 0.f, ay = 0.f;
    for (int i = beg; i < end; ++i) {
        int s = csr_src[i];
        uint v = *(const uint*)(hw + (size_t)s * 128 + lane * 2);
        ax += bflo(v);
        ay += bfhi(v);
    }
    float2 b = *(const float2*)(bias + lane * 2);
    ax = fmaxf(ax + b.x, 0.f);
    ay = fmaxf(ay + b.y, 0.f);
    uint o = (uint)f2bf(ax) | ((uint)f2bf(ay) << 16);
    *(uint*)(hout + (size_t)node * 128 + lane * 2) = o;
}

// ---------------------------------------------------------------------------
// out = log_softmax(logits f32) over 40 cols, one wave per row
// ---------------------------------------------------------------------------
__global__ __launch_bounds__(256) void log_softmax_kernel(
    const float* __restrict__ logits, float* __restrict__ out, int M)
{
    int w    = (int)(((long long)blockIdx.x * 256 + threadIdx.x) >> 6);
    int lane = threadIdx.x & 63;
    if (w >= M) return;
    float v = -3.402823466e38f;
    if (lane < 40) v = logits[(size_t)w * 40 + lane];
    float m = v;
    #pragma unroll
    for (int off = 32; off > 0; off >>= 1) m = fmaxf(m, __shfl_xor(m, off, 64));
    float e = (lane < 40) ? expf(v - m) : 0.f;
    float s = e;
    #pragma unroll
    for (int off = 32; off > 0; off >>= 1) s += __shfl_xor(s, off, 64);
    float ls = logf(s);
    if (lane < 40) out[(size_t)w * 40 + lane] = v - m - ls;
}

// ---------------------------------------------------------------------------
extern "C" void kernel_launch(void* const* d_in, const int* in_sizes, int n_in,
                              void* d_out, int out_size, void* d_ws, size_t ws_size,
                              hipStream_t stream)
{
    const float* x      = (const float*)d_in[0];
    const int*   edge   = (const int*)d_in[1];
    const float* enc_w1 = (const float*)d_in[2];
    const float* enc_b1 = (const float*)d_in[3];
    const float* enc_w2 = (const float*)d_in[4];
    const float* enc_b2 = (const float*)d_in[5];
    const float* gcn_w  = (const float*)d_in[6];
    const float* gcn_b  = (const float*)d_in[7];
    const float* dec_w1 = (const float*)d_in[8];
    const float* dec_b1 = (const float*)d_in[9];
    const float* dec_w2 = (const float*)d_in[10];
    const float* dec_b2 = (const float*)d_in[11];

    const int F_IN = 128, H_ENC = 256, D = 128, N_CLS = 40, R = 3;
    const int N = in_sizes[0] / F_IN;   // 100000
    const int E = in_sizes[1] / 2;      // 600000
    const int* src = edge;
    const int* dst = edge + E;

    // ---- workspace layout (bytes) ----
    char* p = (char*)d_ws;
    ushort* xb     = (ushort*)p;                 p += (size_t)N * 128 * 2;   // 25.6 MB
    ushort* h1     = (ushort*)p;                 p += (size_t)N * 256 * 2;   // 51.2 MB
    ushort* h      = (ushort*)p;                 p += (size_t)N * 128 * 2;   // 25.6 MB
    ushort* hw     = (ushort*)p;                 p += (size_t)N * 128 * 2;   // 25.6 MB
    float*  logits = (float*)p;                  p += (size_t)N * 40 * 4;    // 16.0 MB
    ushort* enc1t  = (ushort*)p;                 p += 256 * 128 * 2;
    ushort* enc2t  = (ushort*)p;                 p += 128 * 256 * 2;
    ushort* gcnt   = (ushort*)p;                 p += 3 * 128 * 128 * 2;
    ushort* dec1t  = (ushort*)p;                 p += 128 * 128 * 2;
    ushort* dec2t  = (ushort*)p;                 p += 48 * 128 * 2;
    int* csr_src   = (int*)p;                    // E ints
    int* rs        = csr_src + E;                // N+1
    int* cnt       = rs + (N + 1);               // N
    int* partials  = cnt + N;                    // <=512

    float* out = (float*)d_out;
    dim3 blk(256);

    // ---- one-time converts ----
    cast_bf16_kernel<<<(N * 128 / 4 + 255) / 256, blk, 0, stream>>>(x, xb, N * 128 / 4);
    wtrans_kernel<<<(256 * 128 + 255) / 256, blk, 0, stream>>>(enc_w1, enc1t, 128, 256, 256);
    wtrans_kernel<<<(128 * 256 + 255) / 256, blk, 0, stream>>>(enc_w2, enc2t, 256, 128, 128);
    for (int r = 0; r < R; ++r)
        wtrans_kernel<<<(128 * 128 + 255) / 256, blk, 0, stream>>>(
            gcn_w + (size_t)r * 128 * 128, gcnt + (size_t)r * 128 * 128, 128, 128, 128);
    wtrans_kernel<<<(128 * 128 + 255) / 256, blk, 0, stream>>>(dec_w1, dec1t, 128, 128, 128);
    wtrans_kernel<<<(48 * 128 + 255) / 256, blk, 0, stream>>>(dec_w2, dec2t, 128, 40, 48);

    // ---- CSR build ----
    const int nblkN = (N + 255) / 256;
    const int nblkE = (E + 255) / 256;
    hipMemsetAsync(cnt, 0, (size_t)N * sizeof(int), stream);
    degree_kernel<<<nblkE, blk, 0, stream>>>(dst, cnt, E);
    scan_block_kernel<<<nblkN, blk, 0, stream>>>(cnt, rs, partials, N);
    scan_partials_kernel<<<1, 512, 0, stream>>>(partials, nblkN);
    add_offsets_kernel<<<nblkN + 1, blk, 0, stream>>>(rs, partials, N, E);
    hipMemsetAsync(cnt, 0, (size_t)N * sizeof(int), stream);
    fill_kernel<<<nblkE, blk, 0, stream>>>(src, dst, rs, cnt, csr_src, E);

    // ---- encoder ----
    const int gmx = (N + 63) / 64;   // 1563 blocks, 64 rows each
    dense_mfma_kernel<true, 16, false, true><<<gmx, blk, 0, stream>>>(
        xb, enc1t, enc_b1, h1, N, 128, 256);
    dense_mfma_kernel<false, 8, false, true><<<gmx, blk, 0, stream>>>(
        h1, enc2t, enc_b2, h, N, 256, 128);

    // ---- 3-hop GCN ----
    const int aggb = (N * 64 + 255) / 256;
    for (int r = 0; r < R; ++r) {
        dense_mfma_kernel<false, 8, false, false><<<gmx, blk, 0, stream>>>(
            h, gcnt + (size_t)r * 128 * 128, nullptr, hw, N, 128, 128);
        gather_agg_kernel<<<aggb, blk, 0, stream>>>(
            hw, csr_src, rs, gcn_b + (size_t)r * 128, h, N);
    }

    // ---- decoder ----
    dense_mfma_kernel<true, 8, false, true><<<gmx, blk, 0, stream>>>(
        h, dec1t, dec_b1, hw /*h2*/, N, 128, 128);
    dense_mfma_kernel<false, 3, true, true><<<gmx, blk, 0, stream>>>(
        hw, dec2t, dec_b2, logits, N, 128, 40);

    const int smb = (N + 3) / 4;
    log_softmax_kernel<<<smb, blk, 0, stream>>>(logits, out, N);
}